// Round 11
// baseline (493.509 us; speedup 1.0000x reference)
//
#include <hip/hip_runtime.h>
#include <stdint.h>

// CIN layers: Xn[b,h,d] = sum_{j,k} W[h,j,k] * X0[b,j,d] * Xi[b,k,d] + bias[h]
// y[d,h] = sum_k Xi*W (mfma_32x32x16, A rows m=b'*16+d, B cols=32h), then
// Xacc += x0[b,j,d]*y.
// R10 audit: all pipes ~35% busy, ~60% stall per stage at 2 waves/SIMD.
// 8 of 12 LDS reads/wave-stage were x0 HALF-WAVE BROADCASTS (32 lanes read the
// same 16B) -- moved to global f32 loads (L1-broadcast, barrier-independent,
// prefetchable) and the bf16 unpack (64 VALU/wave-stage) is gone. Barrier count
// halved by staging 2 j per step into a 4x4KB LDS ring. LDS/block 48KB -> 16KB.
// Grid: 512 blocks = 128 b-groups (XCD-local XiT slice) x 4 h-tiles;
// block = 4 waves x 8 b x 32 h.

#define NB_F0 39
#define NB_H  128
#define NB_B  4096

typedef float f32x4  __attribute__((ext_vector_type(4)));
typedef float f32x16 __attribute__((ext_vector_type(16)));
typedef short s16x8  __attribute__((ext_vector_type(8)));

__device__ __forceinline__ void dma16(const void* g, void* l) {
  __builtin_amdgcn_global_load_lds(
      (const __attribute__((address_space(1))) unsigned int*)g,
      (__attribute__((address_space(3))) unsigned int*)l, 16, 0, 0);
}

__device__ __forceinline__ unsigned short rne_bf16(float f) {
  union { float f; unsigned u; } v; v.f = f;
  return (unsigned short)((v.u + 0x7fffu + ((v.u >> 16) & 1u)) >> 16);
}
__device__ __forceinline__ float bf16_to_f32(unsigned short s) {
  union { unsigned u; float f; } v; v.u = ((unsigned)s) << 16;
  return v.f;
}

// X0 f32 [B][39][16] -> X0T bf16 [B][16][64] (k=j zero-padded, layer-0 A source)
//                    -> X0f f32  [B][39][16] d-PERMUTED (pos<->d swap bits 2,3):
//   a lane's 8 x0 factors for MFMA regs m=0..7 (d=(m&3)+8((m>>2)&1)+4L) are the
//   contiguous f32 run X0f[b][j][L*8 .. L*8+7]. Values are bf16-rounded.
__global__ void prep_x0_kernel(const float* __restrict__ X0g,
                               unsigned short* __restrict__ X0T,
                               float* __restrict__ X0f) {
  const int b = blockIdx.x;
  const int t = threadIdx.x;
  {
    const int d  = t >> 4;
    const int k4 = (t & 15) << 2;
    unsigned short vv[4];
#pragma unroll
    for (int i = 0; i < 4; ++i) {
      const int k = k4 + i;
      vv[i] = (k < NB_F0) ? rne_bf16(X0g[(size_t)b * (NB_F0 * 16) + k * 16 + d])
                          : (unsigned short)0;
    }
    ushort4 pk; pk.x = vv[0]; pk.y = vv[1]; pk.z = vv[2]; pk.w = vv[3];
    *(ushort4*)&X0T[((size_t)b * 16 + d) * 64 + k4] = pk;
  }
  for (int idx = t; idx < NB_F0 * 16; idx += 256) {
    const int j = idx >> 4, pos = idx & 15;
    const int d = (pos & 3) | (((pos >> 3) & 1) << 2) | (((pos >> 2) & 1) << 3);
    X0f[(size_t)b * (NB_F0 * 16) + idx] =
        bf16_to_f32(rne_bf16(X0g[(size_t)b * (NB_F0 * 16) + j * 16 + d]));
  }
}

// W f32 [128][39*Fi] -> Wf bf16 fragment-linear for 32x32x16 B-operand:
//   Wf[(((j*4 + t)*KC16 + c)*64 + lane)*8 + i]
//     = W[h = t*32 + (lane&31)][j, k = c*16 + (lane>>5)*8 + i]   (0 if k>=Fi)
__global__ void prep_w_kernel(const float* __restrict__ Wsrc,
                              unsigned short* __restrict__ Wdst,
                              int Fi, int kshift, int total) {
  int idx = blockIdx.x * 256 + threadIdx.x;
  if (idx >= total) return;
  const int i    = idx & 7;
  const int lane = (idx >> 3) & 63;
  const int c    = (idx >> 9) & ((1 << kshift) - 1);
  const int jt   = idx >> (9 + kshift);
  const int t    = jt & 3;
  const int j    = jt >> 2;
  const int h = t * 32 + (lane & 31);
  const int k = c * 16 + ((lane >> 5) << 3) + i;
  unsigned short v = 0;
  if (k < Fi) v = rne_bf16(Wsrc[(size_t)h * (NB_F0 * Fi) + j * Fi + k]);
  Wdst[idx] = v;
}

template <int FI_PAD, bool STORE_XN>
__global__ __launch_bounds__(256, 2) void cin_layer(
    const unsigned short* __restrict__ Wf,   // fragment-linear W (see prep)
    const unsigned short* __restrict__ XiT,  // [B][16][FI_PAD] bf16
    const float* __restrict__ X0f,           // [B][39][16] f32, d-permuted
    const float* __restrict__ bias,          // [128]
    unsigned short* __restrict__ XnT,        // [B][16][128] bf16 (or unused)
    float* __restrict__ outp)                // d_out + layer*128, stride 384
{
  constexpr int KPASS = FI_PAD / 64;   // 1 or 2 K-passes of 64
  constexpr int KC16  = FI_PAD / 16;   // 16-wide k-chunks total
  constexpr int S     = NB_F0 * KPASS;

  __shared__ __attribute__((aligned(16))) unsigned short Wlds[4][2048]; // 16 KB

  const int tid  = threadIdx.x;
  const int lane = tid & 63;
  const int wv   = tid >> 6;
  const int L    = lane >> 5;       // k-half selector
  const int col  = lane & 31;       // A row m / B col
  const int ht   = blockIdx.x >> 7;            // 0..3 (32 h each)
  const int bblk = (blockIdx.x & 127) * 32;    // 32 b per block
  const int bwave = bblk + wv * 8;             // 8 b per wave

  // ---- W DMA: wave wv stages chunk wv (1 KB) of a 4 KB per-stage tile ----
  auto dma_stage = [&](int s, int buf) {
    const int pass = (KPASS == 2 && s >= NB_F0) ? 1 : 0;
    const int j = s - pass * NB_F0;
    const unsigned short* src =
        Wf + (((size_t)(j * 4 + ht) * KC16) + pass * 4 + wv) * 512 + lane * 8;
    dma16(src, &Wlds[buf][wv * 512]);   // lane i -> +i*16B: fragment order
  };

  // ---- Xi A-fragments: chain P covers b' = 2P + (col>>4); resident regs ----
  s16x8 af[4][4];
  auto load_af = [&](int pass) {
#pragma unroll
    for (int P = 0; P < 4; ++P) {
      const unsigned short* base = XiT +
          ((size_t)(bwave + 2 * P + (col >> 4)) * 16 + (col & 15)) * FI_PAD +
          pass * 64 + L * 8;
#pragma unroll
      for (int c = 0; c < 4; ++c) af[P][c] = *(const s16x8*)(base + c * 16);
    }
  };
  load_af(0);

  f32x16 Xacc[4], kZero;
#pragma unroll
  for (int r = 0; r < 16; ++r) kZero[r] = 0.f;
#pragma unroll
  for (int P = 0; P < 4; ++P) Xacc[P] = kZero;

  // x0 base for this wave's L half (per-chain offsets added per stage)
  const float* const x0w = X0f + (size_t)bwave * (NB_F0 * 16) + L * 8;

  auto stage = [&](int s) {
    const int j = (KPASS == 2 && s >= NB_F0) ? s - NB_F0 : s;
    const unsigned short* wb = &Wlds[s & 3][lane * 8];
    const s16x8 w0 = *(const s16x8*)(wb);
    const s16x8 w1 = *(const s16x8*)(wb + 512);
    const s16x8 w2 = *(const s16x8*)(wb + 1024);
    const s16x8 w3 = *(const s16x8*)(wb + 1536);

#pragma unroll
    for (int P = 0; P < 4; ++P) {
      f32x16 y;
      y = __builtin_amdgcn_mfma_f32_32x32x16_bf16(af[P][0], w0, kZero, 0, 0, 0);
      y = __builtin_amdgcn_mfma_f32_32x32x16_bf16(af[P][1], w1, y, 0, 0, 0);
      y = __builtin_amdgcn_mfma_f32_32x32x16_bf16(af[P][2], w2, y, 0, 0, 0);
      y = __builtin_amdgcn_mfma_f32_32x32x16_bf16(af[P][3], w3, y, 0, 0, 0);

      // x0 scale: regs 0-7 <- b'=2P, 8-15 <- b'=2P+1. Half-wave-broadcast
      // global f32 loads (L1 line shared by 32 lanes), no unpack.
      const float* xp = x0w + ((size_t)(2 * P) * NB_F0 + j) * 16;
      const f32x4 a0 = *(const f32x4*)(xp);
      const f32x4 a1 = *(const f32x4*)(xp + 4);
      const f32x4 b0 = *(const f32x4*)(xp + NB_F0 * 16);
      const f32x4 b1 = *(const f32x4*)(xp + NB_F0 * 16 + 4);
      f32x16 xsc;
#pragma unroll
      for (int i = 0; i < 4; ++i) {
        xsc[i] = a0[i]; xsc[4 + i] = a1[i];
        xsc[8 + i] = b0[i]; xsc[12 + i] = b1[i];
      }
      Xacc[P] = __builtin_elementwise_fma(xsc, y, Xacc[P]);
    }
  };

  // ---- main loop: 2 stages (j's) per barrier, 4x4KB LDS ring ----
  dma_stage(0, 0);
  if (S > 1) dma_stage(1, 1);
  constexpr int NSTEP = (S + 1) / 2;
  for (int t = 0; t < NSTEP; ++t) {
    __syncthreads();                 // publishes buffers (2t)&3, (2t+1)&3
    const int s0 = 2 * t;
    if (s0 + 2 < S) dma_stage(s0 + 2, (s0 + 2) & 3);
    if (s0 + 3 < S) dma_stage(s0 + 3, (s0 + 3) & 3);
    stage(s0);
    if (KPASS == 2 && s0 + 1 == NB_F0) load_af(1);  // af K-window switch
    if (s0 + 1 < S) stage(s0 + 1);
  }

  // ---- epilogue ----
  const float bias_v = bias[ht * 32 + col];
#pragma unroll
  for (int P = 0; P < 4; ++P) {
#pragma unroll
    for (int bh = 0; bh < 2; ++bh) {
      const int b = bwave + 2 * P + bh;
      float v[8];
#pragma unroll
      for (int m = 0; m < 8; ++m) v[m] = Xacc[P][bh * 8 + m] + bias_v;
      if (STORE_XN) {
#pragma unroll
        for (int m = 0; m < 8; ++m) {
          const int d = (m & 3) + 8 * ((m >> 2) & 1) + 4 * L;
          XnT[((size_t)b * 16 + d) * NB_H + ht * 32 + col] = rne_bf16(v[m]);
        }
      }
      float tot = ((v[0] + v[1]) + (v[2] + v[3])) + ((v[4] + v[5]) + (v[6] + v[7]));
      tot += __shfl_xor(tot, 32);
      if (lane < 32) outp[(size_t)b * 384 + ht * 32 + lane] = tot;
    }
  }
}

extern "C" void kernel_launch(void* const* d_in, const int* in_sizes, int n_in,
                              void* d_out, int out_size, void* d_ws, size_t ws_size,
                              hipStream_t stream) {
  (void)in_sizes; (void)n_in; (void)out_size; (void)ws_size;
  const float* X0g = (const float*)d_in[0];
  const float* W0  = (const float*)d_in[1];
  const float* b0  = (const float*)d_in[2];
  const float* W1  = (const float*)d_in[3];
  const float* b1  = (const float*)d_in[4];
  const float* W2  = (const float*)d_in[5];
  const float* b2  = (const float*)d_in[6];
  float* out = (float*)d_out;

  char* p = (char*)d_ws;
  unsigned short* X0T = (unsigned short*)p; p += (size_t)NB_B * 16 * 64 * 2;
  float*          X0f = (float*)p;          p += (size_t)NB_B * NB_F0 * 16 * 4;
  unsigned short* X1T = (unsigned short*)p; p += (size_t)NB_B * 16 * 128 * 2;
  unsigned short* X2T = (unsigned short*)p; p += (size_t)NB_B * 16 * 128 * 2;
  unsigned short* Wf0 = (unsigned short*)p; p += (size_t)NB_F0 * 4 * 4 * 512 * 2;
  unsigned short* Wf1 = (unsigned short*)p; p += (size_t)NB_F0 * 4 * 8 * 512 * 2;
  unsigned short* Wf2 = (unsigned short*)p; p += (size_t)NB_F0 * 4 * 8 * 512 * 2;

  hipLaunchKernelGGL(prep_x0_kernel, dim3(NB_B), dim3(256), 0, stream,
                     X0g, X0T, X0f);
  const int tw0  = NB_F0 * 4 * 4 * 512;   // KC16=4
  const int tw12 = NB_F0 * 4 * 8 * 512;   // KC16=8
  hipLaunchKernelGGL(prep_w_kernel, dim3((tw0 + 255) / 256), dim3(256), 0, stream,
                     W0, Wf0, 39, 2, tw0);
  hipLaunchKernelGGL(prep_w_kernel, dim3((tw12 + 255) / 256), dim3(256), 0, stream,
                     W1, Wf1, 128, 3, tw12);
  hipLaunchKernelGGL(prep_w_kernel, dim3((tw12 + 255) / 256), dim3(256), 0, stream,
                     W2, Wf2, 128, 3, tw12);

  hipLaunchKernelGGL((cin_layer<64, true>),   dim3(512), dim3(256), 0, stream,
                     Wf0, X0T, X0f, b0, X1T, out + 0);
  hipLaunchKernelGGL((cin_layer<128, true>),  dim3(512), dim3(256), 0, stream,
                     Wf1, X1T, X0f, b1, X2T, out + 128);
  hipLaunchKernelGGL((cin_layer<128, false>), dim3(512), dim3(256), 0, stream,
                     Wf2, X2T, X0f, b2, (unsigned short*)nullptr, out + 256);
}